// Round 6
// baseline (472.962 us; speedup 1.0000x reference)
//
#include <hip/hip_runtime.h>
#include <math.h>

// N0=200000 nodes, E0=1000000 edges, feat0 dim 62, RBF 64.
// GAT1: 64 -> [2x8]=16, GAT2: 16 -> [1x64]. g_list[1] branch is dead.
// R5 rewrite: dst-CSR built on device once; both edge passes become
// gather kernels (no f32 device atomics -> WRITE_SIZE 94MB -> ~15MB).

#define LRELU(v) ((v) > 0.0f ? (v) : 0.2f * (v))

// ---------------------------------------------------------------------------
// wl[i] = sum_f W2[i,f]*al2[f]; wr likewise (GAT2 attention via h0 directly)
// ---------------------------------------------------------------------------
__global__ __launch_bounds__(64) void k_prep(const float* __restrict__ W2,
                                             const float* __restrict__ al2,
                                             const float* __restrict__ ar2,
                                             float* __restrict__ wl,
                                             float* __restrict__ wr) {
    int i = threadIdx.x;
    if (i >= 16) return;
    float sl = 0.f, sr = 0.f;
    for (int f = 0; f < 64; ++f) {
        float w = W2[i * 64 + f];
        sl += w * al2[f];
        sr += w * ar2[f];
    }
    wl[i] = sl;
    wr[i] = sr;
}

// ---------------------------------------------------------------------------
// CSR build: histogram -> two-level exclusive scan -> fill
// ---------------------------------------------------------------------------
__global__ __launch_bounds__(256) void k_hist(const int* __restrict__ dst,
                                              int* __restrict__ deg, int E) {
    int e = blockIdx.x * 256 + threadIdx.x;
    if (e < E) atomicAdd(&deg[dst[e]], 1);
}

__global__ __launch_bounds__(1024) void k_scan1(const int* __restrict__ deg,
                                                int* __restrict__ partial,
                                                int N) {
    __shared__ int lds[1024];
    int i = blockIdx.x * 1024 + threadIdx.x;
    lds[threadIdx.x] = (i < N) ? deg[i] : 0;
    __syncthreads();
    for (int s = 512; s > 0; s >>= 1) {
        if (threadIdx.x < s) lds[threadIdx.x] += lds[threadIdx.x + s];
        __syncthreads();
    }
    if (threadIdx.x == 0) partial[blockIdx.x] = lds[0];
}

__global__ __launch_bounds__(256) void k_scan2(const int* __restrict__ partial,
                                               int* __restrict__ partoff,
                                               int nb) {
    __shared__ int lds[256];
    int t = threadIdx.x;
    int v = (t < nb) ? partial[t] : 0;
    lds[t] = v;
    __syncthreads();
    for (int s = 1; s < 256; s <<= 1) {
        int add = (t >= s) ? lds[t - s] : 0;
        __syncthreads();
        lds[t] += add;
        __syncthreads();
    }
    if (t < nb) partoff[t] = lds[t] - v;  // exclusive
}

__global__ __launch_bounds__(1024) void k_scan3(const int* __restrict__ deg,
                                                const int* __restrict__ partoff,
                                                int* __restrict__ off,
                                                int* __restrict__ cur, int N) {
    __shared__ int lds[1024];
    int t = threadIdx.x;
    int i = blockIdx.x * 1024 + t;
    int v = (i < N) ? deg[i] : 0;
    lds[t] = v;
    __syncthreads();
    for (int s = 1; s < 1024; s <<= 1) {
        int add = (t >= s) ? lds[t - s] : 0;
        __syncthreads();
        lds[t] += add;
        __syncthreads();
    }
    if (i < N) {
        int ex = lds[t] - v + partoff[blockIdx.x];
        off[i] = ex;
        cur[i] = ex;
    }
}

__global__ __launch_bounds__(256) void k_fill(const int* __restrict__ src,
                                              const int* __restrict__ dst,
                                              int* __restrict__ cur,
                                              int* __restrict__ csr, int E) {
    int e = blockIdx.x * 256 + threadIdx.x;
    if (e >= E) return;
    int d = dst[e];
    int pos = atomicAdd(&cur[d], 1);
    csr[pos] = src[e];
}

// ---------------------------------------------------------------------------
// Fused: nf = sqrt(2/64)*cos(feat0 @ Wr + br)  (registers only)
//        h1p = nf @ W1 [N,16]; el1/er1 per head
// ---------------------------------------------------------------------------
__global__ __launch_bounds__(256) void k_rbf_proj(
    const float* __restrict__ feat0, const float* __restrict__ Wr,
    const float* __restrict__ br, const float* __restrict__ W1,
    const float* __restrict__ al1, const float* __restrict__ ar1,
    float* __restrict__ h1p, float* __restrict__ el1, float* __restrict__ er1,
    int N) {
    int n = blockIdx.x * blockDim.x + threadIdx.x;
    if (n >= N) return;

    float x[62];
    const float2* fp = reinterpret_cast<const float2*>(feat0 + (size_t)n * 62);
#pragma unroll
    for (int k = 0; k < 31; ++k) {
        float2 v = fp[k];
        x[2 * k] = v.x;
        x[2 * k + 1] = v.y;
    }

    float hp[16];
#pragma unroll
    for (int i = 0; i < 16; ++i) hp[i] = 0.f;

    const float cst = 0.17677669529663687f;  // sqrt(2/64)
#pragma unroll 4
    for (int j = 0; j < 64; ++j) {
        float acc = br[j];
#pragma unroll
        for (int k = 0; k < 62; ++k) acc += x[k] * Wr[k * 64 + j];
        float nfj = cst * cosf(acc);
#pragma unroll
        for (int i = 0; i < 16; ++i) hp[i] += nfj * W1[j * 16 + i];
    }

    float e_l[2] = {0.f, 0.f}, e_r[2] = {0.f, 0.f};
#pragma unroll
    for (int i = 0; i < 16; ++i) {
        e_l[i >> 3] += hp[i] * al1[i];
        e_r[i >> 3] += hp[i] * ar1[i];
    }

    float4* ho = reinterpret_cast<float4*>(h1p + (size_t)n * 16);
    ho[0] = make_float4(hp[0], hp[1], hp[2], hp[3]);
    ho[1] = make_float4(hp[4], hp[5], hp[6], hp[7]);
    ho[2] = make_float4(hp[8], hp[9], hp[10], hp[11]);
    ho[3] = make_float4(hp[12], hp[13], hp[14], hp[15]);
    el1[n * 2 + 0] = e_l[0];
    el1[n * 2 + 1] = e_l[1];
    er1[n * 2 + 0] = e_r[0];
    er1[n * 2 + 1] = e_r[1];
}

// ---------------------------------------------------------------------------
// GAT1 gather (+ fused fin1): 16-lane group per dst node d; lane t=h*8+f.
// num/den accumulated in registers; h0 = relu(num/den + b1); el2/er2 via
// 16-lane shfl reduction against wl/wr. No atomics.
// ---------------------------------------------------------------------------
__global__ __launch_bounds__(256) void k_gat1(
    const int* __restrict__ off, const int* __restrict__ deg,
    const int* __restrict__ csr, const float* __restrict__ el1,
    const float* __restrict__ er1, const float* __restrict__ h1p,
    const float* __restrict__ b1, const float* __restrict__ wl,
    const float* __restrict__ wr, float* __restrict__ h0,
    float* __restrict__ el2, float* __restrict__ er2, int N) {
    int tid = blockIdx.x * 256 + threadIdx.x;
    int d = tid >> 4;
    if (d >= N) return;
    int t = tid & 15, h = t >> 3;
    float erd = er1[d * 2 + h];
    int start = off[d], dg = deg[d];
    float acc = 0.f, den = 0.f;
    for (int j = 0; j < dg; ++j) {
        int s = csr[start + j];
        float a = __expf(LRELU(el1[s * 2 + h] + erd));
        acc += a * h1p[(size_t)s * 16 + t];
        den += a;
    }
    float val = fmaxf(acc / fmaxf(den, 1e-9f) + b1[t], 0.f);
    h0[(size_t)d * 16 + t] = val;
    float pl = val * wl[t], pr = val * wr[t];
#pragma unroll
    for (int m = 1; m < 16; m <<= 1) {
        pl += __shfl_xor(pl, m);
        pr += __shfl_xor(pr, m);
    }
    if (t == 0) {
        el2[d] = pl;
        er2[d] = pr;
    }
}

// ---------------------------------------------------------------------------
// GAT2 gather (+ fused node-mean): grid-stride 16-lane groups; per node
// accumulate num/den in registers, add num/den to block LDS sum, one
// global atomic per block per component.
// ---------------------------------------------------------------------------
__global__ __launch_bounds__(256) void k_gat2(
    const int* __restrict__ off, const int* __restrict__ deg,
    const int* __restrict__ csr, const float* __restrict__ el2,
    const float* __restrict__ er2, const float* __restrict__ h0,
    float* __restrict__ s16, int N) {
    __shared__ float bsum[16];
    if (threadIdx.x < 16) bsum[threadIdx.x] = 0.f;
    __syncthreads();
    int t = threadIdx.x & 15;
    int g = (blockIdx.x * 256 + threadIdx.x) >> 4;
    int ng = (gridDim.x * 256) >> 4;
    float tot = 0.f;
    for (int d = g; d < N; d += ng) {
        float erd = er2[d];
        int start = off[d], dg = deg[d];
        float acc = 0.f, den = 0.f;
        for (int j = 0; j < dg; ++j) {
            int s = csr[start + j];
            float a = __expf(LRELU(el2[s] + erd));
            acc += a * h0[(size_t)s * 16 + t];
            den += a;
        }
        tot += acc / fmaxf(den, 1e-9f);
    }
    atomicAdd(&bsum[t], tot);
    __syncthreads();
    if (threadIdx.x < 16) atomicAdd(&s16[threadIdx.x], bsum[threadIdx.x]);
}

// ---------------------------------------------------------------------------
// Tail: mean -> @W2 + b2 -> relu -> fc1 -> relu -> out
// ---------------------------------------------------------------------------
__global__ __launch_bounds__(64) void k_tail(
    const float* __restrict__ s16, const float* __restrict__ W2,
    const float* __restrict__ b2, const float* __restrict__ fc1w,
    const float* __restrict__ fc1b, const float* __restrict__ outw,
    const float* __restrict__ outb, float* __restrict__ out, float invN) {
    if (threadIdx.x != 0 || blockIdx.x != 0) return;
    float m[16];
#pragma unroll
    for (int i = 0; i < 16; ++i) m[i] = s16[i] * invN;
    float h16[16];
#pragma unroll
    for (int j = 0; j < 16; ++j) h16[j] = 0.f;
    for (int f = 0; f < 64; ++f) {
        float v = b2[f];
#pragma unroll
        for (int i = 0; i < 16; ++i) v += m[i] * W2[i * 64 + f];
        v = fmaxf(v, 0.f);  // relu(mean(out2))
#pragma unroll
        for (int j = 0; j < 16; ++j) h16[j] += v * fc1w[j * 64 + f];
    }
    float o = outb[0];
#pragma unroll
    for (int j = 0; j < 16; ++j) {
        float t = fmaxf(h16[j] + fc1b[j], 0.f);
        o += t * outw[j];
    }
    out[0] = o;
}

extern "C" void kernel_launch(void* const* d_in, const int* in_sizes, int n_in,
                              void* d_out, int out_size, void* d_ws,
                              size_t ws_size, hipStream_t stream) {
    const float* feat0 = (const float*)d_in[3];
    const int* src0 = (const int*)d_in[4];
    const int* dst0 = (const int*)d_in[5];
    const float* Wr = (const float*)d_in[9];
    const float* br = (const float*)d_in[10];
    const float* W1 = (const float*)d_in[19];   // g2c1_W [64,16]
    const float* al1 = (const float*)d_in[20];  // [2,8]
    const float* ar1 = (const float*)d_in[21];
    const float* b1 = (const float*)d_in[22];
    const float* W2 = (const float*)d_in[23];   // g2c2_W [16,64]
    const float* al2 = (const float*)d_in[24];  // [1,64]
    const float* ar2 = (const float*)d_in[25];
    const float* b2 = (const float*)d_in[26];
    const float* fc1w = (const float*)d_in[27];
    const float* fc1b = (const float*)d_in[28];
    const float* outw = (const float*)d_in[29];
    const float* outb = (const float*)d_in[30];

    const int N = in_sizes[3] / 62;
    const int E = in_sizes[4];
    const size_t Nz = (size_t)N;

    // Workspace layout (4B units). Zeroed region: [deg N][s16 16].
    int* ws_i = (int*)d_ws;
    float* ws_f = (float*)d_ws;
    int* deg = ws_i;                    // N
    float* s16 = ws_f + Nz;             // 16
    int* off = ws_i + Nz + 16;          // N
    int* cur = ws_i + 2 * Nz + 16;      // N
    int* partial = ws_i + 3 * Nz + 16;  // 256
    int* partoff = ws_i + 3 * Nz + 272; // 256
    int* csr = ws_i + 3 * Nz + 528;     // E
    float* h1p = ws_f + 3 * Nz + 528 + (size_t)E;   // 16N
    float* el1 = h1p + 16 * Nz;         // 2N
    float* er1 = el1 + 2 * Nz;          // 2N
    float* h0 = er1 + 2 * Nz;           // 16N
    float* el2 = h0 + 16 * Nz;          // N
    float* er2 = el2 + Nz;              // N
    float* wl = er2 + Nz;               // 16
    float* wr = wl + 16;                // 16

    hipMemsetAsync(deg, 0, (Nz + 16) * sizeof(float), stream);

    const int nb_n = (N + 255) / 256;
    const int nb_e = (E + 255) / 256;
    const int nb_scan = (N + 1023) / 1024;  // 196 for N=200000 (<=256)

    k_prep<<<1, 64, 0, stream>>>(W2, al2, ar2, wl, wr);
    k_hist<<<nb_e, 256, 0, stream>>>(dst0, deg, E);
    k_scan1<<<nb_scan, 1024, 0, stream>>>(deg, partial, N);
    k_scan2<<<1, 256, 0, stream>>>(partial, partoff, nb_scan);
    k_scan3<<<nb_scan, 1024, 0, stream>>>(deg, partoff, off, cur, N);
    k_fill<<<nb_e, 256, 0, stream>>>(src0, dst0, cur, csr, E);
    k_rbf_proj<<<nb_n, 256, 0, stream>>>(feat0, Wr, br, W1, al1, ar1, h1p,
                                         el1, er1, N);
    k_gat1<<<(N * 16 + 255) / 256, 256, 0, stream>>>(
        off, deg, csr, el1, er1, h1p, b1, wl, wr, h0, el2, er2, N);
    k_gat2<<<1024, 256, 0, stream>>>(off, deg, csr, el2, er2, h0, s16, N);
    k_tail<<<1, 64, 0, stream>>>(s16, W2, b2, fc1w, fc1b, outw, outb,
                                 (float*)d_out, 1.0f / (float)N);
}

// Round 16
// 471.799 us; speedup vs baseline: 1.0025x; 1.0025x over previous
//
#include <hip/hip_runtime.h>
#include <math.h>

// N0=200000, E0=1000000, feat dim 62, RBF 64. GAT1: 64->[2x8]; GAT2: 16->[1x64].
// g_list[1] branch dead. R7: no CSR. GAT1 = scatter-atomic. GAT2 = den2-scatter
// (1 atomic/edge) + edge-major normalized sum (no per-dst num2). 6 dispatches.

#define LRELU(v) ((v) > 0.0f ? (v) : 0.2f * (v))

// ---------------------------------------------------------------------------
// K1: fused zero-init (num1/den1/den2/s16) + wl/wr prep + RBF + proj + attn
// scalars. Weights staged in LDS (Wr 15.9KB, W1 4KB) to kill per-FMA L1 loads.
// ---------------------------------------------------------------------------
__global__ __launch_bounds__(256) void k_rbf_proj(
    const float* __restrict__ feat0, const float* __restrict__ Wr,
    const float* __restrict__ br, const float* __restrict__ W1,
    const float* __restrict__ al1, const float* __restrict__ ar1,
    const float* __restrict__ W2, const float* __restrict__ al2,
    const float* __restrict__ ar2, float* __restrict__ num1,
    float* __restrict__ den1, float* __restrict__ den2,
    float* __restrict__ s16, float* __restrict__ wl, float* __restrict__ wr,
    float* __restrict__ h1p, float* __restrict__ el1, float* __restrict__ er1,
    int N) {
    __shared__ float sWr[62 * 64];
    __shared__ float sW1[64 * 16];
    __shared__ float sbr[64];
    __shared__ float sal[16], sar[16];

    const int tid = threadIdx.x;
    const int n = blockIdx.x * 256 + tid;

    // Zero-init accumulators (harness poisons ws with 0xAA every launch)
    if (n < N) {
        float4 z4 = make_float4(0.f, 0.f, 0.f, 0.f);
        float4* np = reinterpret_cast<float4*>(num1 + (size_t)n * 16);
        np[0] = z4; np[1] = z4; np[2] = z4; np[3] = z4;
        *reinterpret_cast<float2*>(den1 + n * 2) = make_float2(0.f, 0.f);
        den2[n] = 0.f;
    }
    if (blockIdx.x == 0 && tid < 16) {
        s16[tid] = 0.f;
        float sl = 0.f, sr = 0.f;
        for (int f = 0; f < 64; ++f) {
            float w = W2[tid * 64 + f];
            sl += w * al2[f];
            sr += w * ar2[f];
        }
        wl[tid] = sl;
        wr[tid] = sr;
    }

    // Stage weights to LDS (all threads participate; no early return before sync)
    for (int i = tid; i < 62 * 64; i += 256) sWr[i] = Wr[i];
    for (int i = tid; i < 64 * 16; i += 256) sW1[i] = W1[i];
    if (tid < 64) sbr[tid] = br[tid];
    if (tid < 16) { sal[tid] = al1[tid]; sar[tid] = ar1[tid]; }
    __syncthreads();

    if (n >= N) return;

    float x[62];
    const float2* fp = reinterpret_cast<const float2*>(feat0 + (size_t)n * 62);
#pragma unroll
    for (int k = 0; k < 31; ++k) {
        float2 v = fp[k];
        x[2 * k] = v.x;
        x[2 * k + 1] = v.y;
    }

    float hp[16];
#pragma unroll
    for (int i = 0; i < 16; ++i) hp[i] = 0.f;

    const float cst = 0.17677669529663687f;  // sqrt(2/64)
    for (int j = 0; j < 64; ++j) {
        // 4 independent partial sums to break the FMA dependency chain
        float a0 = 0.f, a1 = 0.f, a2 = 0.f, a3 = 0.f;
#pragma unroll
        for (int k = 0; k < 60; k += 4) {
            a0 += x[k + 0] * sWr[(k + 0) * 64 + j];
            a1 += x[k + 1] * sWr[(k + 1) * 64 + j];
            a2 += x[k + 2] * sWr[(k + 2) * 64 + j];
            a3 += x[k + 3] * sWr[(k + 3) * 64 + j];
        }
        a0 += x[60] * sWr[60 * 64 + j];
        a1 += x[61] * sWr[61 * 64 + j];
        float acc = sbr[j] + ((a0 + a1) + (a2 + a3));
        float nfj = cst * cosf(acc);
#pragma unroll
        for (int i = 0; i < 16; ++i) hp[i] += nfj * sW1[j * 16 + i];
    }

    float e_l[2] = {0.f, 0.f}, e_r[2] = {0.f, 0.f};
#pragma unroll
    for (int i = 0; i < 16; ++i) {
        e_l[i >> 3] += hp[i] * sal[i];
        e_r[i >> 3] += hp[i] * sar[i];
    }

    float4* ho = reinterpret_cast<float4*>(h1p + (size_t)n * 16);
    ho[0] = make_float4(hp[0], hp[1], hp[2], hp[3]);
    ho[1] = make_float4(hp[4], hp[5], hp[6], hp[7]);
    ho[2] = make_float4(hp[8], hp[9], hp[10], hp[11]);
    ho[3] = make_float4(hp[12], hp[13], hp[14], hp[15]);
    *reinterpret_cast<float2*>(el1 + n * 2) = make_float2(e_l[0], e_l[1]);
    *reinterpret_cast<float2*>(er1 + n * 2) = make_float2(e_r[0], e_r[1]);
}

// ---------------------------------------------------------------------------
// K2: GAT1 scatter. 16 lanes/edge, t=h*8+f. num1[d,t] += a*h1p[s,t].
// Softmax max-subtraction elided (shift-invariant; logits O(0.1)).
// ---------------------------------------------------------------------------
__global__ __launch_bounds__(256) void k_edge1(
    const int* __restrict__ src, const int* __restrict__ dst,
    const float* __restrict__ el, const float* __restrict__ er,
    const float* __restrict__ hsrc, float* __restrict__ num,
    float* __restrict__ den, int E) {
    int tid = blockIdx.x * 256 + threadIdx.x;
    int e = tid >> 4;
    if (e >= E) return;
    int t = tid & 15;
    int h = t >> 3;
    int s = src[e], d = dst[e];
    float v = el[s * 2 + h] + er[d * 2 + h];
    v = LRELU(v);
    float a = __expf(v);
    float hv = hsrc[(size_t)s * 16 + t];
    atomicAdd(&num[(size_t)d * 16 + t], a * hv);
    if ((t & 7) == 0) atomicAdd(&den[d * 2 + h], a);
}

// ---------------------------------------------------------------------------
// K3: finalize GAT1: h0 = relu(num/max(den,1e-9)+b1); el2/er2 = h0.wl/.wr
// ---------------------------------------------------------------------------
__global__ __launch_bounds__(256) void k_fin1(
    const float* __restrict__ num, const float* __restrict__ den,
    const float* __restrict__ b1, const float* __restrict__ wl,
    const float* __restrict__ wr, float* __restrict__ h0,
    float* __restrict__ el2, float* __restrict__ er2, int N) {
    int n = blockIdx.x * 256 + threadIdx.x;
    if (n >= N) return;
    float dn0 = fmaxf(den[n * 2 + 0], 1e-9f);
    float dn1 = fmaxf(den[n * 2 + 1], 1e-9f);
    const float4* np = reinterpret_cast<const float4*>(num + (size_t)n * 16);
    float q[16];
#pragma unroll
    for (int v4 = 0; v4 < 4; ++v4) {
        float4 nv = np[v4];
        q[v4 * 4 + 0] = nv.x;
        q[v4 * 4 + 1] = nv.y;
        q[v4 * 4 + 2] = nv.z;
        q[v4 * 4 + 3] = nv.w;
    }
    float sl = 0.f, sr = 0.f;
#pragma unroll
    for (int i = 0; i < 16; ++i) {
        float dn = (i < 8) ? dn0 : dn1;
        float val = fmaxf(q[i] / dn + b1[i], 0.f);
        q[i] = val;
        sl += val * wl[i];
        sr += val * wr[i];
    }
    float4* ho = reinterpret_cast<float4*>(h0 + (size_t)n * 16);
    ho[0] = make_float4(q[0], q[1], q[2], q[3]);
    ho[1] = make_float4(q[4], q[5], q[6], q[7]);
    ho[2] = make_float4(q[8], q[9], q[10], q[11]);
    ho[3] = make_float4(q[12], q[13], q[14], q[15]);
    el2[n] = sl;
    er2[n] = sr;
}

// ---------------------------------------------------------------------------
// K4: GAT2 denominator only: den2[d] += a_e  (1 atomic per edge)
// ---------------------------------------------------------------------------
__global__ __launch_bounds__(256) void k_den2(
    const int* __restrict__ src, const int* __restrict__ dst,
    const float* __restrict__ el2, const float* __restrict__ er2,
    float* __restrict__ den2, int E) {
    int e = blockIdx.x * 256 + threadIdx.x;
    if (e >= E) return;
    float v = el2[src[e]] + er2[dst[e]];
    v = LRELU(v);
    atomicAdd(&den2[dst[e]], __expf(v));
}

// ---------------------------------------------------------------------------
// K5: GAT2 numerator folded into the global mean:
//   s16[t] = sum_e a_e * h0[src_e, t] / den2[dst_e]
// Edge-major grid-stride; register accumulate; wave shfl-reduce; 16 LDS
// atomics/block; 16 global atomics/block. No per-dst num2 array at all.
// ---------------------------------------------------------------------------
__global__ __launch_bounds__(256) void k_pv(
    const int* __restrict__ src, const int* __restrict__ dst,
    const float* __restrict__ el2, const float* __restrict__ er2,
    const float* __restrict__ den2, const float* __restrict__ h0,
    float* __restrict__ s16, int E) {
    __shared__ float bsum[16];
    if (threadIdx.x < 16) bsum[threadIdx.x] = 0.f;
    __syncthreads();
    int t = threadIdx.x & 15;
    int g = (blockIdx.x * 256 + threadIdx.x) >> 4;
    int ng = (gridDim.x * 256) >> 4;
    float tot = 0.f;
    for (int e = g; e < E; e += ng) {
        int s = src[e], d = dst[e];
        float v = el2[s] + er2[d];
        v = LRELU(v);
        float a = __expf(v);
        tot += a * h0[(size_t)s * 16 + t] / den2[d];
    }
    // lanes with equal t within the wave: xor 16, 32
    tot += __shfl_xor(tot, 16);
    tot += __shfl_xor(tot, 32);
    if ((threadIdx.x & 63) < 16) atomicAdd(&bsum[t], tot);
    __syncthreads();
    if (threadIdx.x < 16) atomicAdd(&s16[threadIdx.x], bsum[threadIdx.x]);
}

// ---------------------------------------------------------------------------
// K6: tail: mean -> @W2+b2 -> relu -> fc1 -> relu -> out
// ---------------------------------------------------------------------------
__global__ __launch_bounds__(64) void k_tail(
    const float* __restrict__ s16, const float* __restrict__ W2,
    const float* __restrict__ b2, const float* __restrict__ fc1w,
    const float* __restrict__ fc1b, const float* __restrict__ outw,
    const float* __restrict__ outb, float* __restrict__ out, float invN) {
    if (threadIdx.x != 0 || blockIdx.x != 0) return;
    float m[16];
#pragma unroll
    for (int i = 0; i < 16; ++i) m[i] = s16[i] * invN;
    float h16[16];
#pragma unroll
    for (int j = 0; j < 16; ++j) h16[j] = 0.f;
    for (int f = 0; f < 64; ++f) {
        float v = b2[f];
#pragma unroll
        for (int i = 0; i < 16; ++i) v += m[i] * W2[i * 64 + f];
        v = fmaxf(v, 0.f);  // relu(mean(out2))
#pragma unroll
        for (int j = 0; j < 16; ++j) h16[j] += v * fc1w[j * 64 + f];
    }
    float o = outb[0];
#pragma unroll
    for (int j = 0; j < 16; ++j) {
        float tq = fmaxf(h16[j] + fc1b[j], 0.f);
        o += tq * outw[j];
    }
    out[0] = o;
}

extern "C" void kernel_launch(void* const* d_in, const int* in_sizes, int n_in,
                              void* d_out, int out_size, void* d_ws,
                              size_t ws_size, hipStream_t stream) {
    const float* feat0 = (const float*)d_in[3];
    const int* src0 = (const int*)d_in[4];
    const int* dst0 = (const int*)d_in[5];
    const float* Wr = (const float*)d_in[9];
    const float* br = (const float*)d_in[10];
    const float* W1 = (const float*)d_in[19];   // g2c1_W [64,16]
    const float* al1 = (const float*)d_in[20];  // [2,8]
    const float* ar1 = (const float*)d_in[21];
    const float* b1 = (const float*)d_in[22];
    const float* W2 = (const float*)d_in[23];   // g2c2_W [16,64]
    const float* al2 = (const float*)d_in[24];  // [1,64]
    const float* ar2 = (const float*)d_in[25];
    const float* b2 = (const float*)d_in[26];
    const float* fc1w = (const float*)d_in[27];
    const float* fc1b = (const float*)d_in[28];
    const float* outw = (const float*)d_in[29];
    const float* outb = (const float*)d_in[30];

    const int N = in_sizes[3] / 62;
    const int E = in_sizes[4];
    const size_t Nz = (size_t)N;

    float* ws = (float*)d_ws;
    float* num1 = ws;                    // 16N (zeroed in K1)
    float* den1 = ws + 16 * Nz;          // 2N  (zeroed in K1)
    float* den2 = ws + 18 * Nz;          // N   (zeroed in K1)
    float* s16 = ws + 19 * Nz;           // 16  (zeroed in K1)
    float* wl = ws + 19 * Nz + 16;       // 16  (written in K1)
    float* wr = ws + 19 * Nz + 32;       // 16
    float* h1p = ws + 19 * Nz + 48;      // 16N
    float* el1 = h1p + 16 * Nz;          // 2N
    float* er1 = el1 + 2 * Nz;           // 2N
    float* h0 = er1 + 2 * Nz;            // 16N
    float* el2 = h0 + 16 * Nz;           // N
    float* er2 = el2 + Nz;               // N

    const int nb_n = (N + 255) / 256;
    const int nb_e16 = (int)(((long long)E * 16 + 255) / 256);
    const int nb_e = (E + 255) / 256;

    k_rbf_proj<<<nb_n, 256, 0, stream>>>(feat0, Wr, br, W1, al1, ar1, W2, al2,
                                         ar2, num1, den1, den2, s16, wl, wr,
                                         h1p, el1, er1, N);
    k_edge1<<<nb_e16, 256, 0, stream>>>(src0, dst0, el1, er1, h1p, num1, den1,
                                        E);
    k_fin1<<<nb_n, 256, 0, stream>>>(num1, den1, b1, wl, wr, h0, el2, er2, N);
    k_den2<<<nb_e, 256, 0, stream>>>(src0, dst0, el2, er2, den2, E);
    k_pv<<<2048, 256, 0, stream>>>(src0, dst0, el2, er2, den2, h0, s16, E);
    k_tail<<<1, 64, 0, stream>>>(s16, W2, b2, fc1w, fc1b, outw, outb,
                                 (float*)d_out, 1.0f / (float)N);
}